// Round 6
// baseline (468.727 us; speedup 1.0000x reference)
//
#include <hip/hip_runtime.h>

typedef _Float16 f16;
typedef _Float16 f16x4 __attribute__((ext_vector_type(4)));
typedef _Float16 f16x8 __attribute__((ext_vector_type(8)));
typedef float f32x4 __attribute__((ext_vector_type(4)));

#define EMB 1024
#define SEQL 4096
#define BATCH 4
#define NH 16
#define HD 64
#define BH 64           // BATCH*NH
#define MROWS 16384     // BATCH*SEQL
#define KVSPLIT 16      // l-chunks for split-K kv

#define GLOAD_LDS(gp, lp) \
    __builtin_amdgcn_global_load_lds((const __attribute__((address_space(1))) void*)(gp), \
                                     (__attribute__((address_space(3))) void*)(lp), 16, 0, 0)

// ---------------- fp32 -> fp16 convert ----------------
__global__ void cvt_kernel(const float* __restrict__ in, f16* __restrict__ out, int n4) {
    int i = blockIdx.x * blockDim.x + threadIdx.x;
    if (i < n4) {
        float4 v = ((const float4*)in)[i];
        f16x4 o = { (f16)v.x, (f16)v.y, (f16)v.z, (f16)v.w };
        ((f16x4*)out)[i] = o;
    }
}

struct WPtrs { const float* p[5]; };

__global__ void cvt_w_kernel(WPtrs wp, f16* __restrict__ out) {
    int i = blockIdx.x * blockDim.x + threadIdx.x;
    int wsel = blockIdx.y;
    const float4* src = (const float4*)wp.p[wsel];
    float4 v = src[i];
    f16x4 o = { (f16)v.x, (f16)v.y, (f16)v.z, (f16)v.w };
    ((f16x4*)(out + (size_t)wsel * EMB * EMB))[i] = o;
}

__global__ void zero_kernel(float4* __restrict__ p, int n4) {
    int i = blockIdx.x * blockDim.x + threadIdx.x;
    if (i < n4) p[i] = float4{0.f, 0.f, 0.f, 0.f};
}

// ---------------- 256x256 8-phase MFMA GEMM, 2 counted waits / K-tile ----------------
// R1 structure. Correctness rule (R5 ERRATA): a region's ds_read is only safe if some
// wait retiring that region precedes a BARRIER that precedes the read (cross-wave LDS
// visibility — vmcnt is per-wave). Wait plan (steady; FIFO ledger in journal):
//   entering kt outstanding = {A1(kt), A0(kt+1)} (4 loads)
//   ph1: stage B0(kt+1)          -> 6;  no wait
//   ph2: stage B1(kt+1); W(6)    -> 6;  retires A1(kt)        [covers ph3(kt) reads]
//   ph3: stage A1(kt+1)          -> 8;  no wait
//   ph4: stage A0(kt+2); W(4)    -> 4;  retires A0/B0/B1(kt+1) [covers ph1+ph2(kt+1)]
// Tail: kt==NT-2: ph4 W(2); kt==NT-1: ph2 W(0), no other waits. Prologue W(2) covers
// all of tile 0 (incl. ph2(0)'s B1(0) and ph3(0)'s A1(0)).
// Overwrite safety: every stage lands >=1 collective barrier after its region's last
// reader retirement (readers complete before their phase's MFMA lgkmcnt -> pre-barrier).
// C[m][n] = act( sum_k A[m][k]*Bt[n][k] ), A: MxK row-major, Bt: NxK row-major.
// 512 threads = 8 waves (2M x 4N). LDS: per-operand 2 x [256][64] f16 (128 KiB).
// Staging = half-tile (128 rows x 64 cols) = 2 x global_load_lds(16B)/thread, XOR chunk
// swizzle pre-applied on the global source address; ds_read applies the same XOR.
// MODE 0: fp32 out, row-major            [final Wo GEMM]
// MODE 3: f16 out, merged q|u            (col<1024 -> relu/8 q ; else silu u)
// MODE 4: f16 out, merged kT|vT          (row<1024 -> relu/8 kT ; else vT)

#define FENCE asm volatile("" ::: "memory")
#define WAITV(N) asm volatile("s_waitcnt vmcnt(" #N ")" ::: "memory")
#define BAR do { FENCE; __builtin_amdgcn_s_barrier(); FENCE; } while (0)

template<int MODE>
__global__ __launch_bounds__(512, 2) void gemm_kernel(
    const f16* __restrict__ A, const f16* __restrict__ Bt,
    void* __restrict__ Cv, int M, int N, int K)
{
    __shared__ f16 As[2][256 * 64];
    __shared__ f16 Bs[2][256 * 64];

    const int tid  = threadIdx.x;
    const int lane = tid & 63;
    const int w    = tid >> 6;      // wave 0..7
    const int rw   = lane & 15;
    const int quad = lane >> 4;
    const int wm   = w >> 2;        // 0..1  (64-row slice within quadrant)
    const int wn   = w & 3;         // 0..3  (32-col slice within quadrant)
    const int m0 = blockIdx.y * 256;
    const int n0 = blockIdx.x * 256;
    const size_t Ks = (size_t)K;
    const int NT = K >> 6;

    // staging: thread covers row (w*8 + lane>>3) (+64 for 2nd load),
    // physical chunk lane&7 holds logical chunk (lane&7)^(lane>>3)
    const int srow8 = lane >> 3;
    const int slog  = (lane & 7) ^ srow8;
    const f16* gA = A  + (size_t)(m0 + w * 8 + srow8) * Ks + slog * 8;
    const f16* gB = Bt + (size_t)(n0 + w * 8 + srow8) * Ks + slog * 8;
    const int lst = w * 512;        // f16 units; +4096 for 2nd load

#define STAGE_A(H, T, BUF) do { \
    GLOAD_LDS(gA + (size_t)((H) * 128 +  0) * Ks + (T) * 64, &As[BUF][(H) * 8192 + lst]); \
    GLOAD_LDS(gA + (size_t)((H) * 128 + 64) * Ks + (T) * 64, &As[BUF][(H) * 8192 + 4096 + lst]); \
} while (0)
#define STAGE_B(H, T, BUF) do { \
    GLOAD_LDS(gB + (size_t)((H) * 128 +  0) * Ks + (T) * 64, &Bs[BUF][(H) * 8192 + lst]); \
    GLOAD_LDS(gB + (size_t)((H) * 128 + 64) * Ks + (T) * 64, &Bs[BUF][(H) * 8192 + 4096 + lst]); \
} while (0)

    // fragment read: row r, k-slice s -> slot ((s*4+quad)^(rw&7))*8
    const int rw7   = rw & 7;
    const int s0o   = ( quad      ^ rw7) * 8;
    const int s1o   = ((quad + 4) ^ rw7) * 8;
    const int abase = (wm * 64 + rw) * 64;
    const int bbase = (wn * 32 + rw) * 64;

    f32x4 acc[2][2][4][2] = {};
    f16x8 af[4][2], bf[2][2];

#define READ_A(QM, BUF) do { \
    _Pragma("unroll") \
    for (int mi = 0; mi < 4; ++mi) { \
        af[mi][0] = *(const f16x8*)&As[BUF][(QM) * 8192 + abase + mi * 1024 + s0o]; \
        af[mi][1] = *(const f16x8*)&As[BUF][(QM) * 8192 + abase + mi * 1024 + s1o]; \
    } \
} while (0)
#define READ_B(QN, BUF) do { \
    _Pragma("unroll") \
    for (int nj = 0; nj < 2; ++nj) { \
        bf[nj][0] = *(const f16x8*)&Bs[BUF][(QN) * 8192 + bbase + nj * 1024 + s0o]; \
        bf[nj][1] = *(const f16x8*)&Bs[BUF][(QN) * 8192 + bbase + nj * 1024 + s1o]; \
    } \
} while (0)
#define MFMA_Q(QM, QN) do { \
    __builtin_amdgcn_s_setprio(1); \
    _Pragma("unroll") \
    for (int mi = 0; mi < 4; ++mi) \
        _Pragma("unroll") \
        for (int nj = 0; nj < 2; ++nj) { \
            acc[QM][QN][mi][nj] = __builtin_amdgcn_mfma_f32_16x16x32_f16(bf[nj][0], af[mi][0], acc[QM][QN][mi][nj], 0, 0, 0); \
            acc[QM][QN][mi][nj] = __builtin_amdgcn_mfma_f32_16x16x32_f16(bf[nj][1], af[mi][1], acc[QM][QN][mi][nj], 0, 0, 0); \
        } \
    __builtin_amdgcn_s_setprio(0); \
} while (0)

    // ---- prologue: tile 0 fully + A-h0(1); W(2) leaves only A-h0(1) in flight
    STAGE_A(0, 0, 0);
    STAGE_B(0, 0, 0);
    STAGE_B(1, 0, 0);
    STAGE_A(1, 0, 0);
    if (NT > 1) { STAGE_A(0, 1, 1); WAITV(2); } else { WAITV(0); }
    BAR;

    for (int kt = 0; kt < NT; ++kt) {
        const int cur = kt & 1, nxt = cur ^ 1;
        const bool p1 = (kt + 1 < NT), p2 = (kt + 2 < NT);
        // phase 1: Q(0,0) — reads covered by W(4)@ph4(kt-1) / prologue
        if (p1) STAGE_B(0, kt + 1, nxt);
        READ_A(0, cur); READ_B(0, cur);
        BAR; MFMA_Q(0, 0); BAR;
        // phase 2: Q(0,1) — read covered by W(4)@ph4(kt-1); W here covers ph3's read
        if (p1) STAGE_B(1, kt + 1, nxt);
        READ_B(1, cur);
        if (p1) { WAITV(6); } else { WAITV(0); }
        BAR; MFMA_Q(0, 1); BAR;
        // phase 3: Q(1,1) — read covered by W(6)@ph2
        if (p1) STAGE_A(1, kt + 1, nxt);
        READ_A(1, cur);
        BAR; MFMA_Q(1, 1); BAR;
        // phase 4: Q(1,0) — W here covers ph1+ph2 of kt+1 (A0/B0/B1(kt+1))
        if (p2) STAGE_A(0, kt + 2, cur);
        READ_B(0, cur);
        if (p2) { WAITV(4); } else if (p1) { WAITV(2); }
        BAR; MFMA_Q(1, 0); BAR;
    }

    // ---- epilogue: swapped-operand layout: m = ...+rw ; regs r -> n = ...+quad*4+r
    #pragma unroll
    for (int qm = 0; qm < 2; ++qm)
    #pragma unroll
    for (int qn = 0; qn < 2; ++qn)
    #pragma unroll
    for (int mi = 0; mi < 4; ++mi)
    #pragma unroll
    for (int nj = 0; nj < 2; ++nj) {
        const int m_idx = m0 + qm * 128 + wm * 64 + mi * 16 + rw;
        const int n_idx = n0 + qn * 128 + wn * 32 + nj * 16 + quad * 4;
        f32x4 a = acc[qm][qn][mi][nj];
        if (MODE == 0) {
            float4 vv = { a[0], a[1], a[2], a[3] };
            *(float4*)&((float*)Cv)[(size_t)m_idx * N + n_idx] = vv;
        } else if (MODE == 3) {
            int sel = n_idx >> 10, e = n_idx & 1023;
            int b = m_idx >> 12, l = m_idx & 4095, h = e >> 6, hdi = e & 63;
            f16x4 o;
            #pragma unroll
            for (int r = 0; r < 4; r++) {
                float v = a[r];
                o[r] = (f16)(sel ? (v / (1.0f + __expf(-v))) : (fmaxf(v, 0.0f) * 0.125f));
            }
            *(f16x4*)&((f16*)Cv)[(size_t)sel * MROWS * EMB +
                                 (((size_t)(b * 16 + h) * 4096 + l) << 6) + hdi] = o;
        } else {
            int sel = m_idx >> 10, e = m_idx & 1023;
            int b = n_idx >> 12, l = n_idx & 4095;
            f16x4 o;
            #pragma unroll
            for (int r = 0; r < 4; r++) {
                float v = a[r];
                o[r] = (f16)(sel ? v : (fmaxf(v, 0.0f) * 0.125f));
            }
            *(f16x4*)&((f16*)Cv)[(size_t)sel * MROWS * EMB +
                                 (((size_t)b * 1024 + e) << 12) + l] = o;
        }
    }
#undef STAGE_A
#undef STAGE_B
#undef READ_A
#undef READ_B
#undef MFMA_Q
}

// ---------------- split-K kv: kv[m][n] += sum_{l in chunk} k[l][m]*v[l][n] ----------------
__global__ __launch_bounds__(256) void kv_split_kernel(
    const f16* __restrict__ kT, const f16* __restrict__ vT, float* __restrict__ kv32)
{
    const int bh    = blockIdx.x;
    const int chunk = blockIdx.y;
    const int lane  = threadIdx.x & 63;
    const int w     = threadIdx.x >> 6;
    const int rw    = lane & 15;
    const int quad  = lane >> 4;
    const int lbase = chunk * (SEQL / KVSPLIT);

    const f16* kp = kT + (size_t)bh * HD * SEQL + (size_t)(w * 16 + rw) * SEQL + lbase + quad * 8;
    const f16* vp = vT + (size_t)bh * HD * SEQL + (size_t)rw * SEQL + lbase + quad * 8;

    f32x4 acc[4] = {};
    for (int k0 = 0; k0 < SEQL / KVSPLIT; k0 += 32) {
        f16x8 a = *(const f16x8*)(kp + k0);
        #pragma unroll
        for (int t = 0; t < 4; t++) {
            f16x8 b = *(const f16x8*)(vp + (size_t)16 * t * SEQL + k0);
            acc[t] = __builtin_amdgcn_mfma_f32_16x16x32_f16(a, b, acc[t], 0, 0, 0);
        }
    }
    float* out = kv32 + (size_t)bh * HD * HD;
    #pragma unroll
    for (int t = 0; t < 4; t++)
        #pragma unroll
        for (int r = 0; r < 4; r++)
            atomicAdd(&out[(w * 16 + quad * 4 + r) * 64 + t * 16 + rw], acc[t][r]);
}

// ---------------- out = SRMSNorm(q @ kv) * u, written to (b,l,emb) f16 ----------------
__global__ __launch_bounds__(256) void ret_out_kernel(
    const f16* __restrict__ q, const f16* __restrict__ u,
    const float* __restrict__ kv32, f16* __restrict__ o)
{
    const int bh    = blockIdx.x;
    const int chunk = blockIdx.y;
    const int lane  = threadIdx.x & 63;
    const int w     = threadIdx.x >> 6;
    const int rw    = lane & 15;
    const int quad  = lane >> 4;

    const float* kvp = kv32 + (size_t)bh * 4096;
    f16x8 bf[2][4];
    #pragma unroll
    for (int s = 0; s < 2; s++)
        #pragma unroll
        for (int t = 0; t < 4; t++)
            #pragma unroll
            for (int j = 0; j < 8; j++)
                bf[s][t][j] = (f16)kvp[(s * 32 + quad * 8 + j) * 64 + t * 16 + rw];

    const f16* qp = q + (size_t)bh * SEQL * HD;
    const f16* up = u + (size_t)bh * SEQL * HD;
    const int b = bh >> 4, h = bh & 15;
    f16* op = o + (size_t)b * SEQL * EMB + h * 64;

    const int l_wave = chunk * 512 + w * 128;
    for (int s = 0; s < 8; s++) {
        const int l0 = l_wave + s * 16;
        f16x8 a0 = *(const f16x8*)(qp + (size_t)(l0 + rw) * 64 + quad * 8);
        f16x8 a1 = *(const f16x8*)(qp + (size_t)(l0 + rw) * 64 + 32 + quad * 8);
        f32x4 acc[4] = {};
        #pragma unroll
        for (int t = 0; t < 4; t++) {
            acc[t] = __builtin_amdgcn_mfma_f32_16x16x32_f16(a0, bf[0][t], acc[t], 0, 0, 0);
            acc[t] = __builtin_amdgcn_mfma_f32_16x16x32_f16(a1, bf[1][t], acc[t], 0, 0, 0);
        }
        float inv[4];
        #pragma unroll
        for (int r = 0; r < 4; r++) {
            float ss = acc[0][r] * acc[0][r] + acc[1][r] * acc[1][r]
                     + acc[2][r] * acc[2][r] + acc[3][r] * acc[3][r];
            #pragma unroll
            for (int msk = 1; msk < 16; msk <<= 1)
                ss += __shfl_xor(ss, msk, 16);
            inv[r] = 8.0f / fmaxf(sqrtf(ss), 8e-12f);
        }
        #pragma unroll
        for (int t = 0; t < 4; t++)
            #pragma unroll
            for (int r = 0; r < 4; r++) {
                int l = l0 + quad * 4 + r;
                int col = t * 16 + rw;
                float uval = (float)up[(size_t)l * 64 + col];
                op[(size_t)l * EMB + col] = (f16)(acc[t][r] * inv[r] * uval);
            }
    }
}

extern "C" void kernel_launch(void* const* d_in, const int* in_sizes, int n_in,
                              void* d_out, int out_size, void* d_ws, size_t ws_size,
                              hipStream_t stream)
{
    const float* x = (const float*)d_in[0];
    // dst slot order: Wq, Wu, Wk, Wv, Wo  (so [Wq;Wu] and [Wk;Wv] are contiguous)
    WPtrs wp;
    wp.p[0] = (const float*)d_in[1];  // Wq
    wp.p[1] = (const float*)d_in[4];  // Wu
    wp.p[2] = (const float*)d_in[2];  // Wk
    wp.p[3] = (const float*)d_in[3];  // Wv
    wp.p[4] = (const float*)d_in[5];  // Wo

    char* ws = (char*)d_ws;
    size_t off = 0;
    f16* x16 = (f16*)(ws + off); off += (size_t)MROWS * EMB * 2;
    f16* w16 = (f16*)(ws + off); off += (size_t)5 * EMB * EMB * 2;
    f16* qb  = (f16*)(ws + off); off += (size_t)MROWS * EMB * 2;   // q
    f16* ub  = (f16*)(ws + off); off += (size_t)MROWS * EMB * 2;   // u (contiguous after q)
    f16* kTb = (f16*)(ws + off); off += (size_t)MROWS * EMB * 2;   // kT
    f16* vTb = (f16*)(ws + off); off += (size_t)MROWS * EMB * 2;   // vT (contiguous after kT)
    float* kv32 = (float*)(ws + off); off += (size_t)BH * HD * HD * 4;
    f16* ob  = x16;  // reuse: x16 dead after the two merged projection GEMMs
    (void)ub; (void)vTb;

    cvt_kernel<<<(MROWS * EMB / 4) / 256, 256, 0, stream>>>(x, x16, MROWS * EMB / 4);
    cvt_w_kernel<<<dim3((EMB * EMB / 4) / 256, 5), 256, 0, stream>>>(wp, w16);
    zero_kernel<<<(BH * HD * HD / 4 + 255) / 256, 256, 0, stream>>>((float4*)kv32, BH * HD * HD / 4);

    f16* Wqu = w16;                              // [Wq; Wu]  2048 x 1024
    f16* Wkv = w16 + (size_t)2 * EMB * EMB;      // [Wk; Wv]  2048 x 1024
    f16* Wo  = w16 + (size_t)4 * EMB * EMB;

    dim3 blk(512);
    // q|u = acts(x [Wq;Wu]^T) -> (b,h,l,hd) pair
    gemm_kernel<3><<<dim3(8, 64), blk, 0, stream>>>(x16, Wqu, qb, MROWS, 2 * EMB, EMB);
    // kT|vT = acts([Wk;Wv] x^T) -> (b,h,hd,l) pair
    gemm_kernel<4><<<dim3(64, 8), blk, 0, stream>>>(Wkv, x16, kTb, 2 * EMB, MROWS, EMB);

    // retention core
    kv_split_kernel<<<dim3(BH, KVSPLIT), dim3(256), 0, stream>>>(kTb, vTb, kv32);
    ret_out_kernel<<<dim3(BH, 8), dim3(256), 0, stream>>>(qb, ub, kv32, ob);

    // final: out = o @ Wo^T, fp32
    gemm_kernel<0><<<dim3(4, 64), blk, 0, stream>>>(ob, Wo, d_out, MROWS, EMB, EMB);
}

// Round 7
// 381.917 us; speedup vs baseline: 1.2273x; 1.2273x over previous
//
#include <hip/hip_runtime.h>

typedef _Float16 f16;
typedef _Float16 f16x4 __attribute__((ext_vector_type(4)));
typedef _Float16 f16x8 __attribute__((ext_vector_type(8)));
typedef float f32x4 __attribute__((ext_vector_type(4)));

#define EMB 1024
#define SEQL 4096
#define BATCH 4
#define NH 16
#define HD 64
#define BH 64           // BATCH*NH
#define MROWS 16384     // BATCH*SEQL
#define KVSPLIT 16      // l-chunks for split-K kv

#define GLOAD_LDS(gp, lp) \
    __builtin_amdgcn_global_load_lds((const __attribute__((address_space(1))) void*)(gp), \
                                     (__attribute__((address_space(3))) void*)(lp), 16, 0, 0)

struct WPtrs { const float* p[5]; };

// ---------------- fused prep: x fp32->f16, 5 weights fp32->f16, kv zero ----------------
// range-decoded 1D grid; all section sizes divide the block count exactly.
#define NXB (MROWS * EMB / 4 / 256)        // 16384 blocks
#define NWB (5 * EMB * EMB / 4 / 256)      // 5120 blocks
#define NZB (BH * HD * HD / 4 / 256)       // 256 blocks
__global__ void prep_kernel(const float* __restrict__ x, WPtrs wp,
                            f16* __restrict__ x16, f16* __restrict__ w16,
                            float4* __restrict__ kvz)
{
    int gid = blockIdx.x;
    int t = threadIdx.x;
    if (gid < NXB) {
        int i = gid * 256 + t;
        float4 v = ((const float4*)x)[i];
        f16x4 o = { (f16)v.x, (f16)v.y, (f16)v.z, (f16)v.w };
        ((f16x4*)x16)[i] = o;
    } else if (gid < NXB + NWB) {
        int i = (gid - NXB) * 256 + t;     // 0 .. 5*262144-1
        int wsel = i >> 18;                // 262144 float4 per 1024x1024 weight
        int j = i & 262143;
        float4 v = ((const float4*)wp.p[wsel])[j];
        f16x4 o = { (f16)v.x, (f16)v.y, (f16)v.z, (f16)v.w };
        ((f16x4*)(w16 + (size_t)wsel * EMB * EMB))[j] = o;
    } else {
        int i = (gid - NXB - NWB) * 256 + t;
        kvz[i] = float4{0.f, 0.f, 0.f, 0.f};
    }
}

// ---------------- 256x256 8-phase counted-vmcnt MFMA GEMM (R1 schedule, verbatim) ------
// C[m][n] = act( sum_k A[m][k]*Bt[n][k] ), A: MxK row-major, Bt: NxK row-major.
// 512 threads = 8 waves (2M x 4N). LDS: per-operand 2 x [256][64] f16 (128 KiB).
// Staging = half-tile (128 rows x 64 cols) = 2 x global_load_lds(16B)/thread, XOR chunk
// swizzle pre-applied on the global source address; ds_read applies the same XOR.
// Per K-tile kt (R1 best-measured order: READs, then stage+W(6), 2 barriers/phase):
//   ph1 Q(0,0): read A-h0,B-h0; stage B-h0(kt+1); W6; bar; 16 MFMA; bar
//   ph2 Q(0,1): read B-h1;      stage B-h1(kt+1); W6; bar; 16 MFMA; bar
//   ph3 Q(1,1): read A-h1;      stage A-h1(kt+1); W6; bar; 16 MFMA; bar
//   ph4 Q(1,0): read B-h0;      stage A-h0(kt+2); W6; bar; 16 MFMA; bar
// (R3/R6 lesson: thinning these waits/barriers REGRESSES — 1 block/CU, no cross-block
// overlap; the dense shallow waits keep the 8-wave rotation tight. Do not touch.)
// MODE 0:  fp32 out, row-major                    [final Wo GEMM]
// MODE 34: fused projection pair, 1D grid 1024:
//   blocks 0..511:   A=x16, B=Wqu, (8n x 64m) decode -> q|u epilogue (relu/8, silu)
//   blocks 512..1023: A=Wkv(=Bt+2M), B=x16, (64n x 8m) decode -> kT|vT epilogue

#define FENCE asm volatile("" ::: "memory")
#define WAITV(N) asm volatile("s_waitcnt vmcnt(" #N ")" ::: "memory")
#define BAR do { FENCE; __builtin_amdgcn_s_barrier(); FENCE; } while (0)

template<int MODE>
__global__ __launch_bounds__(512, 2) void gemm_kernel(
    const f16* __restrict__ A, const f16* __restrict__ Bt,
    void* __restrict__ Cv, int M, int N, int K)
{
    __shared__ f16 As[2][256 * 64];
    __shared__ f16 Bs[2][256 * 64];

    const int tid  = threadIdx.x;
    const int lane = tid & 63;
    const int w    = tid >> 6;      // wave 0..7
    const int rw   = lane & 15;
    const int quad = lane >> 4;
    const int wm   = w >> 2;        // 0..1  (64-row slice within quadrant)
    const int wn   = w & 3;         // 0..3  (32-col slice within quadrant)

    // ---- block decode (uniform per block) ----
    const f16* Ap = A;
    const f16* Bp = Bt;
    char* Cp = (char*)Cv;
    bool sel_qu = true;
    int m0, n0;
    if (MODE == 34) {
        int bid = blockIdx.x;
        if (bid < 512) {                       // q|u half: original (8,64) grid
            m0 = (bid >> 3) * 256; n0 = (bid & 7) * 256;
        } else {                               // kT|vT half: original (64,8) grid
            bid -= 512;
            m0 = (bid >> 6) * 256; n0 = (bid & 63) * 256;
            Ap = Bt + (size_t)2 * EMB * EMB;   // Wkv
            Bp = A;                            // x16
            Cp = (char*)Cv + (size_t)2 * MROWS * EMB * 2;   // kTb (qb,ub,kTb,vTb contig)
            sel_qu = false;
        }
    } else {
        m0 = blockIdx.y * 256; n0 = blockIdx.x * 256;
    }
    const size_t Ks = (size_t)K;
    const int NT = K >> 6;

    // staging: thread covers row (w*8 + lane>>3) (+64 for 2nd load),
    // physical chunk lane&7 holds logical chunk (lane&7)^(lane>>3)
    const int srow8 = lane >> 3;
    const int slog  = (lane & 7) ^ srow8;
    const f16* gA = Ap + (size_t)(m0 + w * 8 + srow8) * Ks + slog * 8;
    const f16* gB = Bp + (size_t)(n0 + w * 8 + srow8) * Ks + slog * 8;
    const int lst = w * 512;        // f16 units; +4096 for 2nd load

#define STAGE_A(H, T, BUF) do { \
    GLOAD_LDS(gA + (size_t)((H) * 128 +  0) * Ks + (T) * 64, &As[BUF][(H) * 8192 + lst]); \
    GLOAD_LDS(gA + (size_t)((H) * 128 + 64) * Ks + (T) * 64, &As[BUF][(H) * 8192 + 4096 + lst]); \
} while (0)
#define STAGE_B(H, T, BUF) do { \
    GLOAD_LDS(gB + (size_t)((H) * 128 +  0) * Ks + (T) * 64, &Bs[BUF][(H) * 8192 + lst]); \
    GLOAD_LDS(gB + (size_t)((H) * 128 + 64) * Ks + (T) * 64, &Bs[BUF][(H) * 8192 + 4096 + lst]); \
} while (0)

    // fragment read: row r, k-slice s -> slot ((s*4+quad)^(rw&7))*8
    const int rw7   = rw & 7;
    const int s0o   = ( quad      ^ rw7) * 8;
    const int s1o   = ((quad + 4) ^ rw7) * 8;
    const int abase = (wm * 64 + rw) * 64;
    const int bbase = (wn * 32 + rw) * 64;

    f32x4 acc[2][2][4][2] = {};
    f16x8 af[4][2], bf[2][2];

#define READ_A(QM, BUF) do { \
    _Pragma("unroll") \
    for (int mi = 0; mi < 4; ++mi) { \
        af[mi][0] = *(const f16x8*)&As[BUF][(QM) * 8192 + abase + mi * 1024 + s0o]; \
        af[mi][1] = *(const f16x8*)&As[BUF][(QM) * 8192 + abase + mi * 1024 + s1o]; \
    } \
} while (0)
#define READ_B(QN, BUF) do { \
    _Pragma("unroll") \
    for (int nj = 0; nj < 2; ++nj) { \
        bf[nj][0] = *(const f16x8*)&Bs[BUF][(QN) * 8192 + bbase + nj * 1024 + s0o]; \
        bf[nj][1] = *(const f16x8*)&Bs[BUF][(QN) * 8192 + bbase + nj * 1024 + s1o]; \
    } \
} while (0)
#define MFMA_Q(QM, QN) do { \
    __builtin_amdgcn_s_setprio(1); \
    _Pragma("unroll") \
    for (int mi = 0; mi < 4; ++mi) \
        _Pragma("unroll") \
        for (int nj = 0; nj < 2; ++nj) { \
            acc[QM][QN][mi][nj] = __builtin_amdgcn_mfma_f32_16x16x32_f16(bf[nj][0], af[mi][0], acc[QM][QN][mi][nj], 0, 0, 0); \
            acc[QM][QN][mi][nj] = __builtin_amdgcn_mfma_f32_16x16x32_f16(bf[nj][1], af[mi][1], acc[QM][QN][mi][nj], 0, 0, 0); \
        } \
    __builtin_amdgcn_s_setprio(0); \
} while (0)

    // ---- prologue: tile 0 fully + A-h0(1); W(2) leaves only A-h0(1) in flight
    STAGE_A(0, 0, 0);
    STAGE_B(0, 0, 0);
    STAGE_B(1, 0, 0);
    STAGE_A(1, 0, 0);
    if (NT > 1) { STAGE_A(0, 1, 1); WAITV(2); } else { WAITV(0); }
    BAR;

    for (int kt = 0; kt < NT; ++kt) {
        const int cur = kt & 1, nxt = cur ^ 1;
        const bool p1 = (kt + 1 < NT), p2 = (kt + 2 < NT);
        // phase 1: Q(0,0)
        READ_A(0, cur); READ_B(0, cur);
        if (p1) { STAGE_B(0, kt + 1, nxt); WAITV(6); } else { WAITV(2); }
        BAR; MFMA_Q(0, 0); BAR;
        // phase 2: Q(0,1)
        READ_B(1, cur);
        if (p1) { STAGE_B(1, kt + 1, nxt); WAITV(6); } else { WAITV(0); }
        BAR; MFMA_Q(0, 1); BAR;
        // phase 3: Q(1,1)
        READ_A(1, cur);
        if (p1) { STAGE_A(1, kt + 1, nxt); WAITV(6); } else { WAITV(0); }
        BAR; MFMA_Q(1, 1); BAR;
        // phase 4: Q(1,0)  (A-h0 of kt+2 goes into the CURRENT buffer: h0 reads done at ph1)
        READ_B(0, cur);
        if (p2) { STAGE_A(0, kt + 2, cur); WAITV(6); } else { WAITV(4); }
        BAR; MFMA_Q(1, 0); BAR;
    }

    // ---- epilogue: swapped-operand layout: m = ...+rw ; regs r -> n = ...+quad*4+r
    #pragma unroll
    for (int qm = 0; qm < 2; ++qm)
    #pragma unroll
    for (int qn = 0; qn < 2; ++qn)
    #pragma unroll
    for (int mi = 0; mi < 4; ++mi)
    #pragma unroll
    for (int nj = 0; nj < 2; ++nj) {
        const int m_idx = m0 + qm * 128 + wm * 64 + mi * 16 + rw;
        const int n_idx = n0 + qn * 128 + wn * 32 + nj * 16 + quad * 4;
        f32x4 a = acc[qm][qn][mi][nj];
        if (MODE == 0) {
            float4 vv = { a[0], a[1], a[2], a[3] };
            *(float4*)&((float*)Cv)[(size_t)m_idx * N + n_idx] = vv;
        } else if (sel_qu) {
            // q|u: col<1024 -> relu/8 into q (b,h,l,hd); col>=1024 -> silu into u
            int sel = n_idx >> 10, e = n_idx & 1023;
            int b = m_idx >> 12, l = m_idx & 4095, h = e >> 6, hdi = e & 63;
            f16x4 o;
            #pragma unroll
            for (int r = 0; r < 4; r++) {
                float v = a[r];
                o[r] = (f16)(sel ? (v / (1.0f + __expf(-v))) : (fmaxf(v, 0.0f) * 0.125f));
            }
            *(f16x4*)&((f16*)Cp)[(size_t)sel * MROWS * EMB +
                                 (((size_t)(b * 16 + h) * 4096 + l) << 6) + hdi] = o;
        } else {
            // kT|vT: row<1024 -> relu/8 into kT (b,h,hd,l); row>=1024 -> vT plain
            int sel = m_idx >> 10, e = m_idx & 1023;
            int b = n_idx >> 12, l = n_idx & 4095;
            f16x4 o;
            #pragma unroll
            for (int r = 0; r < 4; r++) {
                float v = a[r];
                o[r] = (f16)(sel ? v : (fmaxf(v, 0.0f) * 0.125f));
            }
            *(f16x4*)&((f16*)Cp)[(size_t)sel * MROWS * EMB +
                                 (((size_t)b * 1024 + e) << 12) + l] = o;
        }
    }
#undef STAGE_A
#undef STAGE_B
#undef READ_A
#undef READ_B
#undef MFMA_Q
}

// ---------------- split-K kv: kv[m][n] += sum_{l in chunk} k[l][m]*v[l][n] ----------------
__global__ __launch_bounds__(256) void kv_split_kernel(
    const f16* __restrict__ kT, const f16* __restrict__ vT, float* __restrict__ kv32)
{
    const int bh    = blockIdx.x;
    const int chunk = blockIdx.y;
    const int lane  = threadIdx.x & 63;
    const int w     = threadIdx.x >> 6;
    const int rw    = lane & 15;
    const int quad  = lane >> 4;
    const int lbase = chunk * (SEQL / KVSPLIT);

    const f16* kp = kT + (size_t)bh * HD * SEQL + (size_t)(w * 16 + rw) * SEQL + lbase + quad * 8;
    const f16* vp = vT + (size_t)bh * HD * SEQL + (size_t)rw * SEQL + lbase + quad * 8;

    f32x4 acc[4] = {};
    for (int k0 = 0; k0 < SEQL / KVSPLIT; k0 += 32) {
        f16x8 a = *(const f16x8*)(kp + k0);
        #pragma unroll
        for (int t = 0; t < 4; t++) {
            f16x8 b = *(const f16x8*)(vp + (size_t)16 * t * SEQL + k0);
            acc[t] = __builtin_amdgcn_mfma_f32_16x16x32_f16(a, b, acc[t], 0, 0, 0);
        }
    }
    float* out = kv32 + (size_t)bh * HD * HD;
    #pragma unroll
    for (int t = 0; t < 4; t++)
        #pragma unroll
        for (int r = 0; r < 4; r++)
            atomicAdd(&out[(w * 16 + quad * 4 + r) * 64 + t * 16 + rw], acc[t][r]);
}

// ---------------- out = SRMSNorm(q @ kv) * u, written to (b,l,emb) f16 ----------------
__global__ __launch_bounds__(256) void ret_out_kernel(
    const f16* __restrict__ q, const f16* __restrict__ u,
    const float* __restrict__ kv32, f16* __restrict__ o)
{
    const int bh    = blockIdx.x;
    const int chunk = blockIdx.y;
    const int lane  = threadIdx.x & 63;
    const int w     = threadIdx.x >> 6;
    const int rw    = lane & 15;
    const int quad  = lane >> 4;

    const float* kvp = kv32 + (size_t)bh * 4096;
    f16x8 bf[2][4];
    #pragma unroll
    for (int s = 0; s < 2; s++)
        #pragma unroll
        for (int t = 0; t < 4; t++)
            #pragma unroll
            for (int j = 0; j < 8; j++)
                bf[s][t][j] = (f16)kvp[(s * 32 + quad * 8 + j) * 64 + t * 16 + rw];

    const f16* qp = q + (size_t)bh * SEQL * HD;
    const f16* up = u + (size_t)bh * SEQL * HD;
    const int b = bh >> 4, h = bh & 15;
    f16* op = o + (size_t)b * SEQL * EMB + h * 64;

    const int l_wave = chunk * 512 + w * 128;
    for (int s = 0; s < 8; s++) {
        const int l0 = l_wave + s * 16;
        f16x8 a0 = *(const f16x8*)(qp + (size_t)(l0 + rw) * 64 + quad * 8);
        f16x8 a1 = *(const f16x8*)(qp + (size_t)(l0 + rw) * 64 + 32 + quad * 8);
        f32x4 acc[4] = {};
        #pragma unroll
        for (int t = 0; t < 4; t++) {
            acc[t] = __builtin_amdgcn_mfma_f32_16x16x32_f16(a0, bf[0][t], acc[t], 0, 0, 0);
            acc[t] = __builtin_amdgcn_mfma_f32_16x16x32_f16(a1, bf[1][t], acc[t], 0, 0, 0);
        }
        float inv[4];
        #pragma unroll
        for (int r = 0; r < 4; r++) {
            float ss = acc[0][r] * acc[0][r] + acc[1][r] * acc[1][r]
                     + acc[2][r] * acc[2][r] + acc[3][r] * acc[3][r];
            #pragma unroll
            for (int msk = 1; msk < 16; msk <<= 1)
                ss += __shfl_xor(ss, msk, 16);
            inv[r] = 8.0f / fmaxf(sqrtf(ss), 8e-12f);
        }
        #pragma unroll
        for (int t = 0; t < 4; t++)
            #pragma unroll
            for (int r = 0; r < 4; r++) {
                int l = l0 + quad * 4 + r;
                int col = t * 16 + rw;
                float uval = (float)up[(size_t)l * 64 + col];
                op[(size_t)l * EMB + col] = (f16)(acc[t][r] * inv[r] * uval);
            }
    }
}

extern "C" void kernel_launch(void* const* d_in, const int* in_sizes, int n_in,
                              void* d_out, int out_size, void* d_ws, size_t ws_size,
                              hipStream_t stream)
{
    const float* x = (const float*)d_in[0];
    // dst slot order: Wq, Wu, Wk, Wv, Wo  (so [Wq;Wu] and [Wk;Wv] are contiguous)
    WPtrs wp;
    wp.p[0] = (const float*)d_in[1];  // Wq
    wp.p[1] = (const float*)d_in[4];  // Wu
    wp.p[2] = (const float*)d_in[2];  // Wk
    wp.p[3] = (const float*)d_in[3];  // Wv
    wp.p[4] = (const float*)d_in[5];  // Wo

    char* ws = (char*)d_ws;
    size_t off = 0;
    f16* x16 = (f16*)(ws + off); off += (size_t)MROWS * EMB * 2;
    f16* w16 = (f16*)(ws + off); off += (size_t)5 * EMB * EMB * 2;
    f16* qb  = (f16*)(ws + off); off += (size_t)MROWS * EMB * 2;   // q
    f16* ub  = (f16*)(ws + off); off += (size_t)MROWS * EMB * 2;   // u (contiguous after q)
    f16* kTb = (f16*)(ws + off); off += (size_t)MROWS * EMB * 2;   // kT
    f16* vTb = (f16*)(ws + off); off += (size_t)MROWS * EMB * 2;   // vT (contiguous after kT)
    float* kv32 = (float*)(ws + off); off += (size_t)BH * HD * HD * 4;
    f16* ob  = x16;  // reuse: x16 dead after the merged projection GEMM
    (void)ub; (void)vTb;

    // fused converts + kv zero-init (one launch)
    prep_kernel<<<NXB + NWB + NZB, 256, 0, stream>>>(x, wp, x16, w16, (float4*)kv32);

    f16* Wo = w16 + (size_t)4 * EMB * EMB;

    // fused projection pair: blocks 0..511 q|u = acts(x [Wq;Wu]^T);
    //                        blocks 512..1023 kT|vT = acts([Wk;Wv] x^T)
    gemm_kernel<34><<<1024, 512, 0, stream>>>(x16, w16, qb, MROWS, 2 * EMB, EMB);

    // retention core
    kv_split_kernel<<<dim3(BH, KVSPLIT), dim3(256), 0, stream>>>(kTb, vTb, kv32);
    ret_out_kernel<<<dim3(BH, 8), dim3(256), 0, stream>>>(qb, ub, kv32, ob);

    // final: out = o @ Wo^T, fp32
    gemm_kernel<0><<<dim3(4, 64), dim3(512), 0, stream>>>(ob, Wo, d_out, MROWS, EMB, EMB);
}

// Round 9
// 376.041 us; speedup vs baseline: 1.2465x; 1.0156x over previous
//
#include <hip/hip_runtime.h>

typedef _Float16 f16;
typedef _Float16 f16x4 __attribute__((ext_vector_type(4)));
typedef _Float16 f16x8 __attribute__((ext_vector_type(8)));
typedef float f32x4 __attribute__((ext_vector_type(4)));

#define EMB 1024
#define SEQL 4096
#define BATCH 4
#define NH 16
#define HD 64
#define BH 64           // BATCH*NH
#define MROWS 16384     // BATCH*SEQL
#define KVSPLIT 16      // l-chunks for split-K kv

#define GLOAD_LDS(gp, lp) \
    __builtin_amdgcn_global_load_lds((const __attribute__((address_space(1))) void*)(gp), \
                                     (__attribute__((address_space(3))) void*)(lp), 16, 0, 0)

struct WPtrs { const float* p[5]; };

// ---------------- fused prep: x fp32->f16, 5 weights fp32->f16, kv zero ----------------
#define NXB (MROWS * EMB / 4 / 256)        // 16384 blocks
#define NWB (5 * EMB * EMB / 4 / 256)      // 5120 blocks
#define NZB (BH * HD * HD / 4 / 256)       // 256 blocks
__global__ void prep_kernel(const float* __restrict__ x, WPtrs wp,
                            f16* __restrict__ x16, f16* __restrict__ w16,
                            float4* __restrict__ kvz)
{
    int gid = blockIdx.x;
    int t = threadIdx.x;
    if (gid < NXB) {
        int i = gid * 256 + t;
        float4 v = ((const float4*)x)[i];
        f16x4 o = { (f16)v.x, (f16)v.y, (f16)v.z, (f16)v.w };
        ((f16x4*)x16)[i] = o;
    } else if (gid < NXB + NWB) {
        int i = (gid - NXB) * 256 + t;
        int wsel = i >> 18;
        int j = i & 262143;
        float4 v = ((const float4*)wp.p[wsel])[j];
        f16x4 o = { (f16)v.x, (f16)v.y, (f16)v.z, (f16)v.w };
        ((f16x4*)(w16 + (size_t)wsel * EMB * EMB))[j] = o;
    } else {
        int i = (gid - NXB - NWB) * 256 + t;
        kvz[i] = float4{0.f, 0.f, 0.f, 0.f};
    }
}

// ---------------- 256x256 8-phase MFMA GEMM, counted waits ONCE per K-tile-ish --------
// R9: R7 source verbatim EXCEPT wait placement (single variable). Intra-phase order
// kept as R1/R7 (ds_reads -> stage -> wait -> BAR -> MFMA -> BAR); waits thinned to the
// m201/m218 pattern: ph2 W(6), ph4 W(4) only.
// Ledger (FIFO; wait->BAR->read rule; stages ph1:B0' ph2:B1' ph3:A1' ph4:A0''):
//   entering kt outstanding = {A1(kt), A0(kt+1)} = 4 loads
//   ph1: stage B0(kt+1) -> 6; no wait  (reads A0/B0(kt) covered by ph4(kt-1) W(4))
//   ph2: stage B1(kt+1) -> 8; W(6) retires A1(kt)            [covers ph3(kt) READ_A1]
//   ph3: stage A1(kt+1) -> 8; no wait
//   ph4: stage A0(kt+2) -> 10; W(4) retires A0/B0/B1(kt+1)   [covers ph1+ph2(kt+1)]
// Tails: kt==NT-2: ph4 W(2) (retires A0/B0/B1(NT-1)); kt==NT-1: ph2 W(0) (retires
// A1(NT-1) for ph3), no other waits. Prologue W(2) covers all of tile 0.
// Overwrite safety unchanged from R1/R7: every stage lands >=2 barriers after its
// region's last reader completion (reads complete before their phase's MFMA).
// MODE 0:  fp32 out, row-major                    [final Wo GEMM]
// MODE 34: fused projection pair, 1D grid 1024:
//   blocks 0..511:   A=x16, B=Wqu -> q|u epilogue (relu/8, silu)
//   blocks 512..1023: A=Wkv, B=x16 -> kT|vT epilogue

#define FENCE asm volatile("" ::: "memory")
#define WAITV(N) asm volatile("s_waitcnt vmcnt(" #N ")" ::: "memory")
#define BAR do { FENCE; __builtin_amdgcn_s_barrier(); FENCE; } while (0)

template<int MODE>
__global__ __launch_bounds__(512, 2) void gemm_kernel(
    const f16* __restrict__ A, const f16* __restrict__ Bt,
    void* __restrict__ Cv, int M, int N, int K)
{
    __shared__ f16 As[2][256 * 64];
    __shared__ f16 Bs[2][256 * 64];

    const int tid  = threadIdx.x;
    const int lane = tid & 63;
    const int w    = tid >> 6;      // wave 0..7
    const int rw   = lane & 15;
    const int quad = lane >> 4;
    const int wm   = w >> 2;
    const int wn   = w & 3;

    // ---- block decode (uniform per block) ----
    const f16* Ap = A;
    const f16* Bp = Bt;
    char* Cp = (char*)Cv;
    bool sel_qu = true;
    int m0, n0;
    if (MODE == 34) {
        int bid = blockIdx.x;
        if (bid < 512) {
            m0 = (bid >> 3) * 256; n0 = (bid & 7) * 256;
        } else {
            bid -= 512;
            m0 = (bid >> 6) * 256; n0 = (bid & 63) * 256;
            Ap = Bt + (size_t)2 * EMB * EMB;   // Wkv
            Bp = A;                            // x16
            Cp = (char*)Cv + (size_t)2 * MROWS * EMB * 2;   // kTb
            sel_qu = false;
        }
    } else {
        m0 = blockIdx.y * 256; n0 = blockIdx.x * 256;
    }
    const size_t Ks = (size_t)K;
    const int NT = K >> 6;

    const int srow8 = lane >> 3;
    const int slog  = (lane & 7) ^ srow8;
    const f16* gA = Ap + (size_t)(m0 + w * 8 + srow8) * Ks + slog * 8;
    const f16* gB = Bp + (size_t)(n0 + w * 8 + srow8) * Ks + slog * 8;
    const int lst = w * 512;

#define STAGE_A(H, T, BUF) do { \
    GLOAD_LDS(gA + (size_t)((H) * 128 +  0) * Ks + (T) * 64, &As[BUF][(H) * 8192 + lst]); \
    GLOAD_LDS(gA + (size_t)((H) * 128 + 64) * Ks + (T) * 64, &As[BUF][(H) * 8192 + 4096 + lst]); \
} while (0)
#define STAGE_B(H, T, BUF) do { \
    GLOAD_LDS(gB + (size_t)((H) * 128 +  0) * Ks + (T) * 64, &Bs[BUF][(H) * 8192 + lst]); \
    GLOAD_LDS(gB + (size_t)((H) * 128 + 64) * Ks + (T) * 64, &Bs[BUF][(H) * 8192 + 4096 + lst]); \
} while (0)

    const int rw7   = rw & 7;
    const int s0o   = ( quad      ^ rw7) * 8;
    const int s1o   = ((quad + 4) ^ rw7) * 8;
    const int abase = (wm * 64 + rw) * 64;
    const int bbase = (wn * 32 + rw) * 64;

    f32x4 acc[2][2][4][2] = {};
    f16x8 af[4][2], bf[2][2];

#define READ_A(QM, BUF) do { \
    _Pragma("unroll") \
    for (int mi = 0; mi < 4; ++mi) { \
        af[mi][0] = *(const f16x8*)&As[BUF][(QM) * 8192 + abase + mi * 1024 + s0o]; \
        af[mi][1] = *(const f16x8*)&As[BUF][(QM) * 8192 + abase + mi * 1024 + s1o]; \
    } \
} while (0)
#define READ_B(QN, BUF) do { \
    _Pragma("unroll") \
    for (int nj = 0; nj < 2; ++nj) { \
        bf[nj][0] = *(const f16x8*)&Bs[BUF][(QN) * 8192 + bbase + nj * 1024 + s0o]; \
        bf[nj][1] = *(const f16x8*)&Bs[BUF][(QN) * 8192 + bbase + nj * 1024 + s1o]; \
    } \
} while (0)
#define MFMA_Q(QM, QN) do { \
    __builtin_amdgcn_s_setprio(1); \
    _Pragma("unroll") \
    for (int mi = 0; mi < 4; ++mi) \
        _Pragma("unroll") \
        for (int nj = 0; nj < 2; ++nj) { \
            acc[QM][QN][mi][nj] = __builtin_amdgcn_mfma_f32_16x16x32_f16(bf[nj][0], af[mi][0], acc[QM][QN][mi][nj], 0, 0, 0); \
            acc[QM][QN][mi][nj] = __builtin_amdgcn_mfma_f32_16x16x32_f16(bf[nj][1], af[mi][1], acc[QM][QN][mi][nj], 0, 0, 0); \
        } \
    __builtin_amdgcn_s_setprio(0); \
} while (0)

    // ---- prologue: tile 0 fully + A-h0(1); W(2) leaves only A-h0(1) in flight
    STAGE_A(0, 0, 0);
    STAGE_B(0, 0, 0);
    STAGE_B(1, 0, 0);
    STAGE_A(1, 0, 0);
    if (NT > 1) { STAGE_A(0, 1, 1); WAITV(2); } else { WAITV(0); }
    BAR;

    for (int kt = 0; kt < NT; ++kt) {
        const int cur = kt & 1, nxt = cur ^ 1;
        const bool p1 = (kt + 1 < NT), p2 = (kt + 2 < NT);
        // phase 1: Q(0,0) — reads covered by ph4(kt-1) W(4) / prologue; no wait here
        READ_A(0, cur); READ_B(0, cur);
        if (p1) STAGE_B(0, kt + 1, nxt);
        BAR; MFMA_Q(0, 0); BAR;
        // phase 2: Q(0,1) — W(6) retires A1(kt) for ph3's reads
        READ_B(1, cur);
        if (p1) { STAGE_B(1, kt + 1, nxt); WAITV(6); } else { WAITV(0); }
        BAR; MFMA_Q(0, 1); BAR;
        // phase 3: Q(1,1) — read covered by ph2's W(6); no wait here
        READ_A(1, cur);
        if (p1) STAGE_A(1, kt + 1, nxt);
        BAR; MFMA_Q(1, 1); BAR;
        // phase 4: Q(1,0) — W(4) retires A0/B0/B1(kt+1) for next tile's ph1+ph2
        READ_B(0, cur);
        if (p2) { STAGE_A(0, kt + 2, cur); WAITV(4); }
        else if (p1) { WAITV(2); }
        BAR; MFMA_Q(1, 0); BAR;
    }

    // ---- epilogue: swapped-operand layout: m = ...+rw ; regs r -> n = ...+quad*4+r
    #pragma unroll
    for (int qm = 0; qm < 2; ++qm)
    #pragma unroll
    for (int qn = 0; qn < 2; ++qn)
    #pragma unroll
    for (int mi = 0; mi < 4; ++mi)
    #pragma unroll
    for (int nj = 0; nj < 2; ++nj) {
        const int m_idx = m0 + qm * 128 + wm * 64 + mi * 16 + rw;
        const int n_idx = n0 + qn * 128 + wn * 32 + nj * 16 + quad * 4;
        f32x4 a = acc[qm][qn][mi][nj];
        if (MODE == 0) {
            float4 vv = { a[0], a[1], a[2], a[3] };
            *(float4*)&((float*)Cv)[(size_t)m_idx * N + n_idx] = vv;
        } else if (sel_qu) {
            int sel = n_idx >> 10, e = n_idx & 1023;
            int b = m_idx >> 12, l = m_idx & 4095, h = e >> 6, hdi = e & 63;
            f16x4 o;
            #pragma unroll
            for (int r = 0; r < 4; r++) {
                float v = a[r];
                o[r] = (f16)(sel ? (v / (1.0f + __expf(-v))) : (fmaxf(v, 0.0f) * 0.125f));
            }
            *(f16x4*)&((f16*)Cp)[(size_t)sel * MROWS * EMB +
                                 (((size_t)(b * 16 + h) * 4096 + l) << 6) + hdi] = o;
        } else {
            int sel = m_idx >> 10, e = m_idx & 1023;
            int b = n_idx >> 12, l = n_idx & 4095;
            f16x4 o;
            #pragma unroll
            for (int r = 0; r < 4; r++) {
                float v = a[r];
                o[r] = (f16)(sel ? v : (fmaxf(v, 0.0f) * 0.125f));
            }
            *(f16x4*)&((f16*)Cp)[(size_t)sel * MROWS * EMB +
                                 (((size_t)b * 1024 + e) << 12) + l] = o;
        }
    }
#undef STAGE_A
#undef STAGE_B
#undef READ_A
#undef READ_B
#undef MFMA_Q
}

// ---------------- split-K kv: kv[m][n] += sum_{l in chunk} k[l][m]*v[l][n] ----------------
__global__ __launch_bounds__(256) void kv_split_kernel(
    const f16* __restrict__ kT, const f16* __restrict__ vT, float* __restrict__ kv32)
{
    const int bh    = blockIdx.x;
    const int chunk = blockIdx.y;
    const int lane  = threadIdx.x & 63;
    const int w     = threadIdx.x >> 6;
    const int rw    = lane & 15;
    const int quad  = lane >> 4;
    const int lbase = chunk * (SEQL / KVSPLIT);

    const f16* kp = kT + (size_t)bh * HD * SEQL + (size_t)(w * 16 + rw) * SEQL + lbase + quad * 8;
    const f16* vp = vT + (size_t)bh * HD * SEQL + (size_t)rw * SEQL + lbase + quad * 8;

    f32x4 acc[4] = {};
    for (int k0 = 0; k0 < SEQL / KVSPLIT; k0 += 32) {
        f16x8 a = *(const f16x8*)(kp + k0);
        #pragma unroll
        for (int t = 0; t < 4; t++) {
            f16x8 b = *(const f16x8*)(vp + (size_t)16 * t * SEQL + k0);
            acc[t] = __builtin_amdgcn_mfma_f32_16x16x32_f16(a, b, acc[t], 0, 0, 0);
        }
    }
    float* out = kv32 + (size_t)bh * HD * HD;
    #pragma unroll
    for (int t = 0; t < 4; t++)
        #pragma unroll
        for (int r = 0; r < 4; r++)
            atomicAdd(&out[(w * 16 + quad * 4 + r) * 64 + t * 16 + rw], acc[t][r]);
}

// ---------------- out = SRMSNorm(q @ kv) * u, written to (b,l,emb) f16 ----------------
__global__ __launch_bounds__(256) void ret_out_kernel(
    const f16* __restrict__ q, const f16* __restrict__ u,
    const float* __restrict__ kv32, f16* __restrict__ o)
{
    const int bh    = blockIdx.x;
    const int chunk = blockIdx.y;
    const int lane  = threadIdx.x & 63;
    const int w     = threadIdx.x >> 6;
    const int rw    = lane & 15;
    const int quad  = lane >> 4;

    const float* kvp = kv32 + (size_t)bh * 4096;
    f16x8 bf[2][4];
    #pragma unroll
    for (int s = 0; s < 2; s++)
        #pragma unroll
        for (int t = 0; t < 4; t++)
            #pragma unroll
            for (int j = 0; j < 8; j++)
                bf[s][t][j] = (f16)kvp[(s * 32 + quad * 8 + j) * 64 + t * 16 + rw];

    const f16* qp = q + (size_t)bh * SEQL * HD;
    const f16* up = u + (size_t)bh * SEQL * HD;
    const int b = bh >> 4, h = bh & 15;
    f16* op = o + (size_t)b * SEQL * EMB + h * 64;

    const int l_wave = chunk * 512 + w * 128;
    for (int s = 0; s < 8; s++) {
        const int l0 = l_wave + s * 16;
        f16x8 a0 = *(const f16x8*)(qp + (size_t)(l0 + rw) * 64 + quad * 8);
        f16x8 a1 = *(const f16x8*)(qp + (size_t)(l0 + rw) * 64 + 32 + quad * 8);
        f32x4 acc[4] = {};
        #pragma unroll
        for (int t = 0; t < 4; t++) {
            acc[t] = __builtin_amdgcn_mfma_f32_16x16x32_f16(a0, bf[0][t], acc[t], 0, 0, 0);
            acc[t] = __builtin_amdgcn_mfma_f32_16x16x32_f16(a1, bf[1][t], acc[t], 0, 0, 0);
        }
        float inv[4];
        #pragma unroll
        for (int r = 0; r < 4; r++) {
            float ss = acc[0][r] * acc[0][r] + acc[1][r] * acc[1][r]
                     + acc[2][r] * acc[2][r] + acc[3][r] * acc[3][r];
            #pragma unroll
            for (int msk = 1; msk < 16; msk <<= 1)
                ss += __shfl_xor(ss, msk, 16);
            inv[r] = 8.0f / fmaxf(sqrtf(ss), 8e-12f);
        }
        #pragma unroll
        for (int t = 0; t < 4; t++)
            #pragma unroll
            for (int r = 0; r < 4; r++) {
                int l = l0 + quad * 4 + r;
                int col = t * 16 + rw;
                float uval = (float)up[(size_t)l * 64 + col];
                op[(size_t)l * EMB + col] = (f16)(acc[t][r] * inv[r] * uval);
            }
    }
}

extern "C" void kernel_launch(void* const* d_in, const int* in_sizes, int n_in,
                              void* d_out, int out_size, void* d_ws, size_t ws_size,
                              hipStream_t stream)
{
    const float* x = (const float*)d_in[0];
    // dst slot order: Wq, Wu, Wk, Wv, Wo  (so [Wq;Wu] and [Wk;Wv] are contiguous)
    WPtrs wp;
    wp.p[0] = (const float*)d_in[1];  // Wq
    wp.p[1] = (const float*)d_in[4];  // Wu
    wp.p[2] = (const float*)d_in[2];  // Wk
    wp.p[3] = (const float*)d_in[3];  // Wv
    wp.p[4] = (const float*)d_in[5];  // Wo

    char* ws = (char*)d_ws;
    size_t off = 0;
    f16* x16 = (f16*)(ws + off); off += (size_t)MROWS * EMB * 2;
    f16* w16 = (f16*)(ws + off); off += (size_t)5 * EMB * EMB * 2;
    f16* qb  = (f16*)(ws + off); off += (size_t)MROWS * EMB * 2;   // q
    f16* ub  = (f16*)(ws + off); off += (size_t)MROWS * EMB * 2;   // u
    f16* kTb = (f16*)(ws + off); off += (size_t)MROWS * EMB * 2;   // kT
    f16* vTb = (f16*)(ws + off); off += (size_t)MROWS * EMB * 2;   // vT
    float* kv32 = (float*)(ws + off); off += (size_t)BH * HD * HD * 4;
    f16* ob  = x16;  // reuse: x16 dead after the merged projection GEMM
    (void)ub; (void)vTb;

    // fused converts + kv zero-init (one launch)
    prep_kernel<<<NXB + NWB + NZB, 256, 0, stream>>>(x, wp, x16, w16, (float4*)kv32);

    f16* Wo = w16 + (size_t)4 * EMB * EMB;

    // fused projection pair
    gemm_kernel<34><<<1024, 512, 0, stream>>>(x16, w16, qb, MROWS, 2 * EMB, EMB);

    // retention core
    kv_split_kernel<<<dim3(BH, KVSPLIT), dim3(256), 0, stream>>>(kTb, vTb, kv32);
    ret_out_kernel<<<dim3(BH, 8), dim3(256), 0, stream>>>(qb, ub, kv32, ob);

    // final: out = o @ Wo^T, fp32
    gemm_kernel<0><<<dim3(4, 64), dim3(512), 0, stream>>>(ob, Wo, d_out, MROWS, EMB, EMB);
}

// Round 10
// 371.799 us; speedup vs baseline: 1.2607x; 1.0114x over previous
//
#include <hip/hip_runtime.h>

typedef _Float16 f16;
typedef _Float16 f16x4 __attribute__((ext_vector_type(4)));
typedef _Float16 f16x8 __attribute__((ext_vector_type(8)));
typedef float f32x4 __attribute__((ext_vector_type(4)));

#define EMB 1024
#define SEQL 4096
#define BATCH 4
#define NH 16
#define HD 64
#define BH 64           // BATCH*NH
#define MROWS 16384     // BATCH*SEQL
#define KVSPLIT 4       // l-chunks for split-K kv (R10: 16->4, 4x fewer atomics, still 256 blocks)

#define GLOAD_LDS(gp, lp) \
    __builtin_amdgcn_global_load_lds((const __attribute__((address_space(1))) void*)(gp), \
                                     (__attribute__((address_space(3))) void*)(lp), 16, 0, 0)

struct WPtrs { const float* p[5]; };

// ---------------- fused prep: x fp32->f16, 5 weights fp32->f16, kv zero ----------------
#define NXB (MROWS * EMB / 4 / 256)        // 16384 blocks
#define NWB (5 * EMB * EMB / 4 / 256)      // 5120 blocks
#define NZB (BH * HD * HD / 4 / 256)       // 256 blocks
__global__ void prep_kernel(const float* __restrict__ x, WPtrs wp,
                            f16* __restrict__ x16, f16* __restrict__ w16,
                            float4* __restrict__ kvz)
{
    int gid = blockIdx.x;
    int t = threadIdx.x;
    if (gid < NXB) {
        int i = gid * 256 + t;
        float4 v = ((const float4*)x)[i];
        f16x4 o = { (f16)v.x, (f16)v.y, (f16)v.z, (f16)v.w };
        ((f16x4*)x16)[i] = o;
    } else if (gid < NXB + NWB) {
        int i = (gid - NXB) * 256 + t;
        int wsel = i >> 18;
        int j = i & 262143;
        float4 v = ((const float4*)wp.p[wsel])[j];
        f16x4 o = { (f16)v.x, (f16)v.y, (f16)v.z, (f16)v.w };
        ((f16x4*)(w16 + (size_t)wsel * EMB * EMB))[j] = o;
    } else {
        int i = (gid - NXB - NWB) * 256 + t;
        kvz[i] = float4{0.f, 0.f, 0.f, 0.f};
    }
}

// ---------------- 256x256 8-phase MFMA GEMM (R9 schedule, LOCKED) --------------------
// Schedule history: R1 dense-W6 95.8µs; R3 3-barrier 112 (regress); R6 thin+reorder
// 126 (regress); R9 thin-waits-only ~flat/slightly better -> locked as-is.
// Intra-phase order: ds_reads -> stage -> [wait] -> BAR -> 16 MFMA -> BAR.
// Waits: ph2 W(6) (covers ph3's READ_A1), ph4 W(4) (covers next ph1+ph2). Prologue
// W(2); tails ph4 W(2) @NT-2, ph2 W(0) @NT-1. Ledger verified (wait->BAR->read rule).
// MODE 0:  fp32 out, row-major                    [final Wo GEMM]
// MODE 34: fused projection pair, 1D grid 1024:
//   blocks 0..511:   A=x16, B=Wqu -> q|u epilogue (relu/8, silu)
//   blocks 512..1023: A=Wkv, B=x16 -> kT|vT epilogue

#define FENCE asm volatile("" ::: "memory")
#define WAITV(N) asm volatile("s_waitcnt vmcnt(" #N ")" ::: "memory")
#define BAR do { FENCE; __builtin_amdgcn_s_barrier(); FENCE; } while (0)

template<int MODE>
__global__ __launch_bounds__(512, 2) void gemm_kernel(
    const f16* __restrict__ A, const f16* __restrict__ Bt,
    void* __restrict__ Cv, int M, int N, int K)
{
    __shared__ f16 As[2][256 * 64];
    __shared__ f16 Bs[2][256 * 64];

    const int tid  = threadIdx.x;
    const int lane = tid & 63;
    const int w    = tid >> 6;      // wave 0..7
    const int rw   = lane & 15;
    const int quad = lane >> 4;
    const int wm   = w >> 2;
    const int wn   = w & 3;

    // ---- block decode (uniform per block) ----
    const f16* Ap = A;
    const f16* Bp = Bt;
    char* Cp = (char*)Cv;
    bool sel_qu = true;
    int m0, n0;
    if (MODE == 34) {
        int bid = blockIdx.x;
        if (bid < 512) {
            m0 = (bid >> 3) * 256; n0 = (bid & 7) * 256;
        } else {
            bid -= 512;
            m0 = (bid >> 6) * 256; n0 = (bid & 63) * 256;
            Ap = Bt + (size_t)2 * EMB * EMB;   // Wkv
            Bp = A;                            // x16
            Cp = (char*)Cv + (size_t)2 * MROWS * EMB * 2;   // kTb
            sel_qu = false;
        }
    } else {
        m0 = blockIdx.y * 256; n0 = blockIdx.x * 256;
    }
    const size_t Ks = (size_t)K;
    const int NT = K >> 6;

    const int srow8 = lane >> 3;
    const int slog  = (lane & 7) ^ srow8;
    const f16* gA = Ap + (size_t)(m0 + w * 8 + srow8) * Ks + slog * 8;
    const f16* gB = Bp + (size_t)(n0 + w * 8 + srow8) * Ks + slog * 8;
    const int lst = w * 512;

#define STAGE_A(H, T, BUF) do { \
    GLOAD_LDS(gA + (size_t)((H) * 128 +  0) * Ks + (T) * 64, &As[BUF][(H) * 8192 + lst]); \
    GLOAD_LDS(gA + (size_t)((H) * 128 + 64) * Ks + (T) * 64, &As[BUF][(H) * 8192 + 4096 + lst]); \
} while (0)
#define STAGE_B(H, T, BUF) do { \
    GLOAD_LDS(gB + (size_t)((H) * 128 +  0) * Ks + (T) * 64, &Bs[BUF][(H) * 8192 + lst]); \
    GLOAD_LDS(gB + (size_t)((H) * 128 + 64) * Ks + (T) * 64, &Bs[BUF][(H) * 8192 + 4096 + lst]); \
} while (0)

    const int rw7   = rw & 7;
    const int s0o   = ( quad      ^ rw7) * 8;
    const int s1o   = ((quad + 4) ^ rw7) * 8;
    const int abase = (wm * 64 + rw) * 64;
    const int bbase = (wn * 32 + rw) * 64;

    f32x4 acc[2][2][4][2] = {};
    f16x8 af[4][2], bf[2][2];

#define READ_A(QM, BUF) do { \
    _Pragma("unroll") \
    for (int mi = 0; mi < 4; ++mi) { \
        af[mi][0] = *(const f16x8*)&As[BUF][(QM) * 8192 + abase + mi * 1024 + s0o]; \
        af[mi][1] = *(const f16x8*)&As[BUF][(QM) * 8192 + abase + mi * 1024 + s1o]; \
    } \
} while (0)
#define READ_B(QN, BUF) do { \
    _Pragma("unroll") \
    for (int nj = 0; nj < 2; ++nj) { \
        bf[nj][0] = *(const f16x8*)&Bs[BUF][(QN) * 8192 + bbase + nj * 1024 + s0o]; \
        bf[nj][1] = *(const f16x8*)&Bs[BUF][(QN) * 8192 + bbase + nj * 1024 + s1o]; \
    } \
} while (0)
#define MFMA_Q(QM, QN) do { \
    __builtin_amdgcn_s_setprio(1); \
    _Pragma("unroll") \
    for (int mi = 0; mi < 4; ++mi) \
        _Pragma("unroll") \
        for (int nj = 0; nj < 2; ++nj) { \
            acc[QM][QN][mi][nj] = __builtin_amdgcn_mfma_f32_16x16x32_f16(bf[nj][0], af[mi][0], acc[QM][QN][mi][nj], 0, 0, 0); \
            acc[QM][QN][mi][nj] = __builtin_amdgcn_mfma_f32_16x16x32_f16(bf[nj][1], af[mi][1], acc[QM][QN][mi][nj], 0, 0, 0); \
        } \
    __builtin_amdgcn_s_setprio(0); \
} while (0)

    // ---- prologue: tile 0 fully + A-h0(1); W(2) leaves only A-h0(1) in flight
    STAGE_A(0, 0, 0);
    STAGE_B(0, 0, 0);
    STAGE_B(1, 0, 0);
    STAGE_A(1, 0, 0);
    if (NT > 1) { STAGE_A(0, 1, 1); WAITV(2); } else { WAITV(0); }
    BAR;

    for (int kt = 0; kt < NT; ++kt) {
        const int cur = kt & 1, nxt = cur ^ 1;
        const bool p1 = (kt + 1 < NT), p2 = (kt + 2 < NT);
        // phase 1: Q(0,0) — reads covered by ph4(kt-1) W(4) / prologue; no wait here
        READ_A(0, cur); READ_B(0, cur);
        if (p1) STAGE_B(0, kt + 1, nxt);
        BAR; MFMA_Q(0, 0); BAR;
        // phase 2: Q(0,1) — W(6) retires A1(kt) for ph3's reads
        READ_B(1, cur);
        if (p1) { STAGE_B(1, kt + 1, nxt); WAITV(6); } else { WAITV(0); }
        BAR; MFMA_Q(0, 1); BAR;
        // phase 3: Q(1,1) — read covered by ph2's W(6); no wait here
        READ_A(1, cur);
        if (p1) STAGE_A(1, kt + 1, nxt);
        BAR; MFMA_Q(1, 1); BAR;
        // phase 4: Q(1,0) — W(4) retires A0/B0/B1(kt+1) for next tile's ph1+ph2
        READ_B(0, cur);
        if (p2) { STAGE_A(0, kt + 2, cur); WAITV(4); }
        else if (p1) { WAITV(2); }
        BAR; MFMA_Q(1, 0); BAR;
    }

    // ---- epilogue: swapped-operand layout: m = ...+rw ; regs r -> n = ...+quad*4+r
    #pragma unroll
    for (int qm = 0; qm < 2; ++qm)
    #pragma unroll
    for (int qn = 0; qn < 2; ++qn)
    #pragma unroll
    for (int mi = 0; mi < 4; ++mi)
    #pragma unroll
    for (int nj = 0; nj < 2; ++nj) {
        const int m_idx = m0 + qm * 128 + wm * 64 + mi * 16 + rw;
        const int n_idx = n0 + qn * 128 + wn * 32 + nj * 16 + quad * 4;
        f32x4 a = acc[qm][qn][mi][nj];
        if (MODE == 0) {
            float4 vv = { a[0], a[1], a[2], a[3] };
            *(float4*)&((float*)Cv)[(size_t)m_idx * N + n_idx] = vv;
        } else if (sel_qu) {
            int sel = n_idx >> 10, e = n_idx & 1023;
            int b = m_idx >> 12, l = m_idx & 4095, h = e >> 6, hdi = e & 63;
            f16x4 o;
            #pragma unroll
            for (int r = 0; r < 4; r++) {
                float v = a[r];
                o[r] = (f16)(sel ? (v / (1.0f + __expf(-v))) : (fmaxf(v, 0.0f) * 0.125f));
            }
            *(f16x4*)&((f16*)Cp)[(size_t)sel * MROWS * EMB +
                                 (((size_t)(b * 16 + h) * 4096 + l) << 6) + hdi] = o;
        } else {
            int sel = m_idx >> 10, e = m_idx & 1023;
            int b = n_idx >> 12, l = n_idx & 4095;
            f16x4 o;
            #pragma unroll
            for (int r = 0; r < 4; r++) {
                float v = a[r];
                o[r] = (f16)(sel ? v : (fmaxf(v, 0.0f) * 0.125f));
            }
            *(f16x4*)&((f16*)Cp)[(size_t)sel * MROWS * EMB +
                                 (((size_t)b * 1024 + e) << 12) + l] = o;
        }
    }
#undef STAGE_A
#undef STAGE_B
#undef READ_A
#undef READ_B
#undef MFMA_Q
}

// ---------------- split-K kv: kv[m][n] += sum_{l in chunk} k[l][m]*v[l][n] ----------------
__global__ __launch_bounds__(256) void kv_split_kernel(
    const f16* __restrict__ kT, const f16* __restrict__ vT, float* __restrict__ kv32)
{
    const int bh    = blockIdx.x;
    const int chunk = blockIdx.y;
    const int lane  = threadIdx.x & 63;
    const int w     = threadIdx.x >> 6;
    const int rw    = lane & 15;
    const int quad  = lane >> 4;
    const int lbase = chunk * (SEQL / KVSPLIT);

    const f16* kp = kT + (size_t)bh * HD * SEQL + (size_t)(w * 16 + rw) * SEQL + lbase + quad * 8;
    const f16* vp = vT + (size_t)bh * HD * SEQL + (size_t)rw * SEQL + lbase + quad * 8;

    f32x4 acc[4] = {};
    for (int k0 = 0; k0 < SEQL / KVSPLIT; k0 += 32) {
        f16x8 a = *(const f16x8*)(kp + k0);
        #pragma unroll
        for (int t = 0; t < 4; t++) {
            f16x8 b = *(const f16x8*)(vp + (size_t)16 * t * SEQL + k0);
            acc[t] = __builtin_amdgcn_mfma_f32_16x16x32_f16(a, b, acc[t], 0, 0, 0);
        }
    }
    float* out = kv32 + (size_t)bh * HD * HD;
    #pragma unroll
    for (int t = 0; t < 4; t++)
        #pragma unroll
        for (int r = 0; r < 4; r++)
            atomicAdd(&out[(w * 16 + quad * 4 + r) * 64 + t * 16 + rw], acc[t][r]);
}

// ---------------- out = SRMSNorm(q @ kv) * u, written to (b,l,emb) f16 ----------------
// R10: mfma operand order SWAPPED (kv first, q second) — fragments are layout-identical,
// but the output remaps to: lane rw -> row l = l0+rw ; reg (t,r) -> col = t*16+quad*4+r.
// Each lane owns ONE full row: one norm per lane (2 shuffles: xor16, xor32 across the
// 4 quads sharing rw), f16x4 vector u-loads and stores (4 per lane vs 16 scalar).
__global__ __launch_bounds__(256) void ret_out_kernel(
    const f16* __restrict__ q, const f16* __restrict__ u,
    const float* __restrict__ kv32, f16* __restrict__ o)
{
    const int bh    = blockIdx.x;
    const int chunk = blockIdx.y;
    const int lane  = threadIdx.x & 63;
    const int w     = threadIdx.x >> 6;
    const int rw    = lane & 15;
    const int quad  = lane >> 4;

    // kv fragments: bf[s][t][j] = kv[s*32+quad*8+j][t*16+rw]
    // As FIRST mfma arg: P[row=lane&15 -> n-within-tile][k=quad*8+j] = kvT[n][k]  ✓
    const float* kvp = kv32 + (size_t)bh * 4096;
    f16x8 bf[2][4];
    #pragma unroll
    for (int s = 0; s < 2; s++)
        #pragma unroll
        for (int t = 0; t < 4; t++)
            #pragma unroll
            for (int j = 0; j < 8; j++)
                bf[s][t][j] = (f16)kvp[(s * 32 + quad * 8 + j) * 64 + t * 16 + rw];

    const f16* qp = q + (size_t)bh * SEQL * HD;
    const f16* up = u + (size_t)bh * SEQL * HD;
    const int b = bh >> 4, h = bh & 15;
    f16* op = o + (size_t)b * SEQL * EMB + h * 64;

    const int l_wave = chunk * 512 + w * 128;
    for (int s = 0; s < 8; s++) {
        const int l0 = l_wave + s * 16;
        // Q as SECOND arg: rows = lane&15 -> l = l0+rw, k = quad*8+j  ✓
        f16x8 a0 = *(const f16x8*)(qp + (size_t)(l0 + rw) * 64 + quad * 8);
        f16x8 a1 = *(const f16x8*)(qp + (size_t)(l0 + rw) * 64 + 32 + quad * 8);
        f32x4 acc[4] = {};
        #pragma unroll
        for (int t = 0; t < 4; t++) {
            acc[t] = __builtin_amdgcn_mfma_f32_16x16x32_f16(bf[0][t], a0, acc[t], 0, 0, 0);
            acc[t] = __builtin_amdgcn_mfma_f32_16x16x32_f16(bf[1][t], a1, acc[t], 0, 0, 0);
        }
        // row l = l0+rw fully held across this lane's 16 regs + 3 sibling quads
        float ss = 0.f;
        #pragma unroll
        for (int t = 0; t < 4; t++)
            #pragma unroll
            for (int r = 0; r < 4; r++)
                ss += acc[t][r] * acc[t][r];
        ss += __shfl_xor(ss, 16);
        ss += __shfl_xor(ss, 32);
        const float inv = 8.0f / fmaxf(sqrtf(ss), 8e-12f);
        #pragma unroll
        for (int t = 0; t < 4; t++) {
            const int col = t * 16 + quad * 4;
            f16x4 uv = *(const f16x4*)(up + (size_t)(l0 + rw) * 64 + col);
            f16x4 o4;
            #pragma unroll
            for (int r = 0; r < 4; r++)
                o4[r] = (f16)(acc[t][r] * inv * (float)uv[r]);
            *(f16x4*)&op[(size_t)(l0 + rw) * EMB + col] = o4;
        }
    }
}

extern "C" void kernel_launch(void* const* d_in, const int* in_sizes, int n_in,
                              void* d_out, int out_size, void* d_ws, size_t ws_size,
                              hipStream_t stream)
{
    const float* x = (const float*)d_in[0];
    // dst slot order: Wq, Wu, Wk, Wv, Wo  (so [Wq;Wu] and [Wk;Wv] are contiguous)
    WPtrs wp;
    wp.p[0] = (const float*)d_in[1];  // Wq
    wp.p[1] = (const float*)d_in[4];  // Wu
    wp.p[2] = (const float*)d_in[2];  // Wk
    wp.p[3] = (const float*)d_in[3];  // Wv
    wp.p[4] = (const float*)d_in[5];  // Wo

    char* ws = (char*)d_ws;
    size_t off = 0;
    f16* x16 = (f16*)(ws + off); off += (size_t)MROWS * EMB * 2;
    f16* w16 = (f16*)(ws + off); off += (size_t)5 * EMB * EMB * 2;
    f16* qb  = (f16*)(ws + off); off += (size_t)MROWS * EMB * 2;   // q
    f16* ub  = (f16*)(ws + off); off += (size_t)MROWS * EMB * 2;   // u
    f16* kTb = (f16*)(ws + off); off += (size_t)MROWS * EMB * 2;   // kT
    f16* vTb = (f16*)(ws + off); off += (size_t)MROWS * EMB * 2;   // vT
    float* kv32 = (float*)(ws + off); off += (size_t)BH * HD * HD * 4;
    f16* ob  = x16;  // reuse: x16 dead after the merged projection GEMM
    (void)ub; (void)vTb;

    // fused converts + kv zero-init (one launch)
    prep_kernel<<<NXB + NWB + NZB, 256, 0, stream>>>(x, wp, x16, w16, (float4*)kv32);

    f16* Wo = w16 + (size_t)4 * EMB * EMB;

    // fused projection pair
    gemm_kernel<34><<<1024, 512, 0, stream>>>(x16, w16, qb, MROWS, 2 * EMB, EMB);

    // retention core
    kv_split_kernel<<<dim3(BH, KVSPLIT), dim3(256), 0, stream>>>(kTb, vTb, kv32);
    ret_out_kernel<<<dim3(BH, 8), dim3(256), 0, stream>>>(qb, ub, kv32, ob);

    // final: out = o @ Wo^T, fp32
    gemm_kernel<0><<<dim3(4, 64), dim3(512), 0, stream>>>(ob, Wo, d_out, MROWS, EMB, EMB);
}